// Round 7
// baseline (298.479 us; speedup 1.0000x reference)
//
#include <hip/hip_runtime.h>

// 2D DWT (db2, symmetric pad, pywt-compatible) v7: TI=2 — loop-free strips.
// x: (16,3,1024,1024) f32 -> cA, cH: (16,3,513,513) f32, concatenated in d_out.
//
// Confirmed ladder: v3 310.7 (occupancy) -> v5 306.7 (depth-2 ring) ->
// v6 298.3 (TI 8->4, drain-tail granularity). v7 rides granularity to TI=2:
//  - 257x48 = 12336 blocks, T_block ~9us, ~6.9 passes -> drain tail ~2us.
//  - Strip needs exactly 6 xp rows = 3 prologue pairs A,B,C. Row i0 = f(A,B),
//    row i0+1 = f(B,C). NO loop, NO ring rotation, NO loop-carried deps:
//    all 12 loads issue before the first waitcnt (max MLP by construction).
//  - Read amplification 2.5 -> 3 rows/output, but R6 proved overlap re-reads
//    are L3-resident (FETCH ~107MB << 201MB input) -> no HBM cost.
// Kept verbatim: 256 thr, wave-private LDS bounce, dense dword stores, LB(256,7).

#define N 1024
#define NOUT 513
#define TI 2
#define STRIPS ((NOUT + TI - 1) / TI)   // 257 (strip 256 = single row 512)
#define NIMG 48

__device__ __forceinline__ int refl(int p) {
    int r = p - 2;
    r = (r < 0) ? (-1 - r) : r;
    r = (r > N - 1) ? (2 * N - 1 - r) : r;
    return r;
}

__device__ __forceinline__ float4 comb4(float w0, const float4 a, float w1, const float4 b,
                                        float w2, const float4 c, float w3, const float4 d) {
    float4 r;
    r.x = fmaf(w0, a.x, fmaf(w1, b.x, fmaf(w2, c.x, w3 * d.x)));
    r.y = fmaf(w0, a.y, fmaf(w1, b.y, fmaf(w2, c.y, w3 * d.y)));
    r.z = fmaf(w0, a.z, fmaf(w1, b.z, fmaf(w2, c.z, w3 * d.z)));
    r.w = fmaf(w0, a.w, fmaf(w1, b.w, fmaf(w2, c.w, w3 * d.w)));
    return r;
}

__device__ __forceinline__ float2 comb2(float w0, const float2 a, float w1, const float2 b,
                                        float w2, const float2 c, float w3, const float2 d) {
    float2 r;
    r.x = fmaf(w0, a.x, fmaf(w1, b.x, fmaf(w2, c.x, w3 * d.x)));
    r.y = fmaf(w0, a.y, fmaf(w1, b.y, fmaf(w2, c.y, w3 * d.y)));
    return r;
}

__global__ __launch_bounds__(256, 7) void dwt2_v7(const float* __restrict__ x,
                                                  float* __restrict__ out) {
    // reversed filter taps (true convolution)
    const float l0 =  0.48296291314469025f;
    const float l1 =  0.836516303737469f;
    const float l2 =  0.22414386804185735f;
    const float l3 = -0.12940952255092145f;
    const float h0 = -0.12940952255092145f;
    const float h1 = -0.22414386804185735f;
    const float h2 =  0.836516303737469f;
    const float h3 = -0.48296291314469025f;

    __shared__ float sA[4][2][128];   // [wave][row][col] 4 KB
    __shared__ float sH[4][2][128];   // 4 KB

    const int strip = blockIdx.x;
    const int img   = blockIdx.y;
    const int i0 = strip * TI;
    const int u    = threadIdx.x;        // 0..255
    const int wave = u >> 6;
    const int lane = u & 63;
    const int c4 = 4 * u;                // owned input cols c4..c4+3
    const int ce = (u == 0) ? 0 : (c4 - 2);

    const float* xim = x + (size_t)img * N * N;
    const size_t plane = (size_t)NOUT * NOUT;
    float* cA = out + (size_t)img * plane;
    float* cH = out + ((size_t)NIMG + img) * plane;

    // all 6 xp rows for this strip: A=(2i0,2i0+1), B=(2i0+2,2i0+3), C=(2i0+4,2i0+5)
    // 12 independent load instructions, zero dependencies between them.
    const float* q;
    q = xim + (size_t)refl(2 * i0)     * N;
    float4 A0m = *reinterpret_cast<const float4*>(q + c4);
    float2 A0e = *reinterpret_cast<const float2*>(q + ce);
    q = xim + (size_t)refl(2 * i0 + 1) * N;
    float4 A1m = *reinterpret_cast<const float4*>(q + c4);
    float2 A1e = *reinterpret_cast<const float2*>(q + ce);
    q = xim + (size_t)refl(2 * i0 + 2) * N;
    float4 B0m = *reinterpret_cast<const float4*>(q + c4);
    float2 B0e = *reinterpret_cast<const float2*>(q + ce);
    q = xim + (size_t)refl(2 * i0 + 3) * N;
    float4 B1m = *reinterpret_cast<const float4*>(q + c4);
    float2 B1e = *reinterpret_cast<const float2*>(q + ce);
    q = xim + (size_t)refl(2 * i0 + 4) * N;
    float4 C0m = *reinterpret_cast<const float4*>(q + c4);
    float2 C0e = *reinterpret_cast<const float2*>(q + ce);
    q = xim + (size_t)refl(2 * i0 + 5) * N;
    float4 C1m = *reinterpret_cast<const float4*>(q + c4);
    float2 C1e = *reinterpret_cast<const float2*>(q + ce);

    if (i0 + 1 < NOUT) {
        // ---- full strip: rows i0 (v* from A,B) and i0+1 (w* from B,C) ----
        float4 vloM = comb4(l0, A0m, l1, A1m, l2, B0m, l3, B1m);
        float2 vloE = comb2(l0, A0e, l1, A1e, l2, B0e, l3, B1e);
        float4 vhiM = comb4(h0, A0m, h1, A1m, h2, B0m, h3, B1m);
        float2 vhiE = comb2(h0, A0e, h1, A1e, h2, B0e, h3, B1e);
        float4 wloM = comb4(l0, B0m, l1, B1m, l2, C0m, l3, C1m);
        float2 wloE = comb2(l0, B0e, l1, B1e, l2, C0e, l3, C1e);
        float4 whiM = comb4(h0, B0m, h1, B1m, h2, C0m, h3, C1m);
        float2 whiE = comb2(h0, B0e, h1, B1e, h2, C0e, h3, C1e);

        if (u == 0) {   // left image edge: j=0 uses xp cols (1,0,0,1)
            vloE = make_float2(vloM.y, vloM.x);
            vhiE = make_float2(vhiM.y, vhiM.x);
            wloE = make_float2(wloM.y, wloM.x);
            whiE = make_float2(whiM.y, whiM.x);
        }

        // horizontals: row i0 -> j=2u,2u+1 (+512 on u=255); row i0+1 same
        float oA0 = fmaf(l0, vloE.x, fmaf(l1, vloE.y, fmaf(l2, vloM.x, l3 * vloM.y)));
        float oA1 = fmaf(l0, vloM.x, fmaf(l1, vloM.y, fmaf(l2, vloM.z, l3 * vloM.w)));
        float oH0 = fmaf(l0, vhiE.x, fmaf(l1, vhiE.y, fmaf(l2, vhiM.x, l3 * vhiM.y)));
        float oH1 = fmaf(l0, vhiM.x, fmaf(l1, vhiM.y, fmaf(l2, vhiM.z, l3 * vhiM.w)));
        float eA0 = fmaf(l0, vloM.z, fmaf(l1, vloM.w, fmaf(l2, vloM.w, l3 * vloM.z)));
        float eH0 = fmaf(l0, vhiM.z, fmaf(l1, vhiM.w, fmaf(l2, vhiM.w, l3 * vhiM.z)));
        float oA2 = fmaf(l0, wloE.x, fmaf(l1, wloE.y, fmaf(l2, wloM.x, l3 * wloM.y)));
        float oA3 = fmaf(l0, wloM.x, fmaf(l1, wloM.y, fmaf(l2, wloM.z, l3 * wloM.w)));
        float oH2 = fmaf(l0, whiE.x, fmaf(l1, whiE.y, fmaf(l2, whiM.x, l3 * whiM.y)));
        float oH3 = fmaf(l0, whiM.x, fmaf(l1, whiM.y, fmaf(l2, whiM.z, l3 * whiM.w)));
        float eA1 = fmaf(l0, wloM.z, fmaf(l1, wloM.w, fmaf(l2, wloM.w, l3 * wloM.z)));
        float eH1 = fmaf(l0, whiM.z, fmaf(l1, whiM.w, fmaf(l2, whiM.w, l3 * whiM.z)));

        // wave-private LDS bounce -> lane-dense dword stores
        sA[wave][0][2 * lane]     = oA0;
        sA[wave][0][2 * lane + 1] = oA1;
        sA[wave][1][2 * lane]     = oA2;
        sA[wave][1][2 * lane + 1] = oA3;
        sH[wave][0][2 * lane]     = oH0;
        sH[wave][0][2 * lane + 1] = oH1;
        sH[wave][1][2 * lane]     = oH2;
        sH[wave][1][2 * lane + 1] = oH3;
        float rA0 = sA[wave][0][lane];
        float rA1 = sA[wave][0][64 + lane];
        float rA2 = sA[wave][1][lane];
        float rA3 = sA[wave][1][64 + lane];
        float rH0 = sH[wave][0][lane];
        float rH1 = sH[wave][0][64 + lane];
        float rH2 = sH[wave][1][lane];
        float rH3 = sH[wave][1][64 + lane];

        const int j0 = (wave << 7) + lane;
        float* pa0 = cA + (size_t)i0 * NOUT;
        float* pa1 = pa0 + NOUT;
        float* ph0 = cH + (size_t)i0 * NOUT;
        float* ph1 = ph0 + NOUT;
        pa0[j0]      = rA0;
        pa0[j0 + 64] = rA1;
        pa1[j0]      = rA2;
        pa1[j0 + 64] = rA3;
        ph0[j0]      = rH0;
        ph0[j0 + 64] = rH1;
        ph1[j0]      = rH2;
        ph1[j0 + 64] = rH3;

        if (u == 255) {   // right image edge j=512, both rows
            pa0[512] = eA0; ph0[512] = eH0;
            pa1[512] = eA1; ph1[512] = eH1;
        }
    } else {
        // ---- strip 256: single output row i = 512 (uses A,B only) ----
        const int i = i0;
        float4 vloM = comb4(l0, A0m, l1, A1m, l2, B0m, l3, B1m);
        float2 vloE = comb2(l0, A0e, l1, A1e, l2, B0e, l3, B1e);
        float4 vhiM = comb4(h0, A0m, h1, A1m, h2, B0m, h3, B1m);
        float2 vhiE = comb2(h0, A0e, h1, A1e, h2, B0e, h3, B1e);
        if (u == 0) {
            vloE = make_float2(vloM.y, vloM.x);
            vhiE = make_float2(vhiM.y, vhiM.x);
        }
        float oA0 = fmaf(l0, vloE.x, fmaf(l1, vloE.y, fmaf(l2, vloM.x, l3 * vloM.y)));
        float oA1 = fmaf(l0, vloM.x, fmaf(l1, vloM.y, fmaf(l2, vloM.z, l3 * vloM.w)));
        float oH0 = fmaf(l0, vhiE.x, fmaf(l1, vhiE.y, fmaf(l2, vhiM.x, l3 * vhiM.y)));
        float oH1 = fmaf(l0, vhiM.x, fmaf(l1, vhiM.y, fmaf(l2, vhiM.z, l3 * vhiM.w)));
        float* pa = cA + (size_t)i * NOUT;
        float* ph = cH + (size_t)i * NOUT;
        pa[2 * u]     = oA0;
        pa[2 * u + 1] = oA1;
        ph[2 * u]     = oH0;
        ph[2 * u + 1] = oH1;
        if (u == 255) {
            pa[512] = fmaf(l0, vloM.z, fmaf(l1, vloM.w, fmaf(l2, vloM.w, l3 * vloM.z)));
            ph[512] = fmaf(l0, vhiM.z, fmaf(l1, vhiM.w, fmaf(l2, vhiM.w, l3 * vhiM.z)));
        }
        (void)C0m; (void)C0e; (void)C1m; (void)C1e;
    }
}

extern "C" void kernel_launch(void* const* d_in, const int* in_sizes, int n_in,
                              void* d_out, int out_size, void* d_ws, size_t ws_size,
                              hipStream_t stream) {
    (void)in_sizes; (void)n_in; (void)d_ws; (void)ws_size; (void)out_size;
    const float* x = (const float*)d_in[0];
    float* out = (float*)d_out;
    dim3 grid(STRIPS, NIMG);    // 257 x 48 = 12336 blocks
    dim3 block(256);
    dwt2_v7<<<grid, block, 0, stream>>>(x, out);
}